// Round 1
// baseline (207.543 us; speedup 1.0000x reference)
//
#include <hip/hip_runtime.h>

#define HW_PIX (512 * 512)
#define NUM_CLASSES 4
#define IGNORE_INDEX 4

__global__ __launch_bounds__(256) void ce_main_kernel(
    const float* __restrict__ pred,
    const int* __restrict__ target,
    const int* __restrict__ me,
    float* __restrict__ accum,
    int n_groups) {
  int g = blockIdx.x * blockDim.x + threadIdx.x;

  float lsum = 0.0f;
  float lcnt = 0.0f;

  if (g < n_groups) {
    int pg = g << 2;               // first pixel of this 4-pixel group
    int b = pg >> 18;              // / (512*512)
    int p = pg & (HW_PIX - 1);     // % (512*512)

    const float* base = pred + (size_t)b * NUM_CLASSES * HW_PIX + p;
    float4 c0 = *reinterpret_cast<const float4*>(base);
    float4 c1 = *reinterpret_cast<const float4*>(base + HW_PIX);
    float4 c2 = *reinterpret_cast<const float4*>(base + 2 * HW_PIX);
    float4 c3 = *reinterpret_cast<const float4*>(base + 3 * HW_PIX);

    const size_t tbase = (size_t)b * HW_PIX + p;
    int4 tg = *reinterpret_cast<const int4*>(target + tbase);
    int4 mg = *reinterpret_cast<const int4*>(me + tbase);

#define DO_PIXEL(X0, X1, X2, X3, T, M)                                     \
    do {                                                                   \
      int t_ = (T);                                                        \
      if (t_ != IGNORE_INDEX) {                                            \
        float m_ = fmaxf(fmaxf((X0), (X1)), fmaxf((X2), (X3)));            \
        float e_ = __expf((X0) - m_) + __expf((X1) - m_) +                 \
                   __expf((X2) - m_) + __expf((X3) - m_);                  \
        float lse_ = m_ + logf(e_);                                        \
        float xt_ = (t_ == 0) ? (X0) : (t_ == 1) ? (X1)                    \
                  : (t_ == 2) ? (X2) : (X3);                               \
        float w_ = ((M) == 0) ? 1.0f : 0.5f;                               \
        lsum += w_ * (lse_ - xt_);                                         \
        lcnt += 1.0f;                                                      \
      }                                                                    \
    } while (0)

    DO_PIXEL(c0.x, c1.x, c2.x, c3.x, tg.x, mg.x);
    DO_PIXEL(c0.y, c1.y, c2.y, c3.y, tg.y, mg.y);
    DO_PIXEL(c0.z, c1.z, c2.z, c3.z, tg.z, mg.z);
    DO_PIXEL(c0.w, c1.w, c2.w, c3.w, tg.w, mg.w);
#undef DO_PIXEL
  }

  // wave-64 butterfly reduce
  for (int off = 32; off > 0; off >>= 1) {
    lsum += __shfl_down(lsum, off, 64);
    lcnt += __shfl_down(lcnt, off, 64);
  }

  __shared__ float s_sum[4];
  __shared__ float s_cnt[4];
  int wid = threadIdx.x >> 6;
  int lane = threadIdx.x & 63;
  if (lane == 0) {
    s_sum[wid] = lsum;
    s_cnt[wid] = lcnt;
  }
  __syncthreads();

  if (threadIdx.x == 0) {
    float ts = s_sum[0] + s_sum[1] + s_sum[2] + s_sum[3];
    float tc = s_cnt[0] + s_cnt[1] + s_cnt[2] + s_cnt[3];
    atomicAdd(&accum[0], ts);
    atomicAdd(&accum[1], tc);
  }
}

__global__ void ce_final_kernel(const float* __restrict__ accum,
                                float* __restrict__ out) {
  out[0] = accum[0] / accum[1];
}

extern "C" void kernel_launch(void* const* d_in, const int* in_sizes, int n_in,
                              void* d_out, int out_size, void* d_ws, size_t ws_size,
                              hipStream_t stream) {
  const float* pred = (const float*)d_in[0];
  const int* target = (const int*)d_in[1];
  const int* me = (const int*)d_in[2];
  float* accum = (float*)d_ws;
  float* out = (float*)d_out;

  // zero the two accumulators (ws is re-poisoned to 0xAA before every launch)
  hipMemsetAsync(accum, 0, 2 * sizeof(float), stream);

  int total_pixels = in_sizes[1];       // B*H*W = 4,194,304
  int n_groups = total_pixels >> 2;     // 4 pixels per thread
  int block = 256;
  int grid = (n_groups + block - 1) / block;

  ce_main_kernel<<<grid, block, 0, stream>>>(pred, target, me, accum, n_groups);
  ce_final_kernel<<<1, 1, 0, stream>>>(accum, out);
}

// Round 2
// 118.780 us; speedup vs baseline: 1.7473x; 1.7473x over previous
//
#include <hip/hip_runtime.h>

#define HW_PIX (512 * 512)
#define NUM_CLASSES 4
#define IGNORE_INDEX 4
#define NBLOCKS 1024

__global__ __launch_bounds__(256) void ce_main_kernel(
    const float* __restrict__ pred,
    const int* __restrict__ target,
    const int* __restrict__ me,
    float* __restrict__ partials,   // [NBLOCKS * 2]
    int n_groups) {
  float lsum = 0.0f;
  float lcnt = 0.0f;

  const int stride = gridDim.x * blockDim.x;
  for (int g = blockIdx.x * blockDim.x + threadIdx.x; g < n_groups; g += stride) {
    int pg = g << 2;               // first pixel of this 4-pixel group
    int b = pg >> 18;              // / (512*512)
    int p = pg & (HW_PIX - 1);     // % (512*512)

    const float* base = pred + (size_t)b * NUM_CLASSES * HW_PIX + p;
    float4 c0 = *reinterpret_cast<const float4*>(base);
    float4 c1 = *reinterpret_cast<const float4*>(base + HW_PIX);
    float4 c2 = *reinterpret_cast<const float4*>(base + 2 * HW_PIX);
    float4 c3 = *reinterpret_cast<const float4*>(base + 3 * HW_PIX);

    const size_t tbase = (size_t)b * HW_PIX + p;
    int4 tg = *reinterpret_cast<const int4*>(target + tbase);
    int4 mg = *reinterpret_cast<const int4*>(me + tbase);

#define DO_PIXEL(X0, X1, X2, X3, T, M)                                     \
    do {                                                                   \
      int t_ = (T);                                                        \
      if (t_ != IGNORE_INDEX) {                                            \
        float m_ = fmaxf(fmaxf((X0), (X1)), fmaxf((X2), (X3)));            \
        float e_ = __expf((X0) - m_) + __expf((X1) - m_) +                 \
                   __expf((X2) - m_) + __expf((X3) - m_);                  \
        float lse_ = m_ + __logf(e_);                                      \
        float xt_ = (t_ == 0) ? (X0) : (t_ == 1) ? (X1)                    \
                  : (t_ == 2) ? (X2) : (X3);                               \
        float w_ = ((M) == 0) ? 1.0f : 0.5f;                               \
        lsum += w_ * (lse_ - xt_);                                         \
        lcnt += 1.0f;                                                      \
      }                                                                    \
    } while (0)

    DO_PIXEL(c0.x, c1.x, c2.x, c3.x, tg.x, mg.x);
    DO_PIXEL(c0.y, c1.y, c2.y, c3.y, tg.y, mg.y);
    DO_PIXEL(c0.z, c1.z, c2.z, c3.z, tg.z, mg.z);
    DO_PIXEL(c0.w, c1.w, c2.w, c3.w, tg.w, mg.w);
#undef DO_PIXEL
  }

  // wave-64 butterfly reduce
  for (int off = 32; off > 0; off >>= 1) {
    lsum += __shfl_down(lsum, off, 64);
    lcnt += __shfl_down(lcnt, off, 64);
  }

  __shared__ float s_sum[4];
  __shared__ float s_cnt[4];
  int wid = threadIdx.x >> 6;
  int lane = threadIdx.x & 63;
  if (lane == 0) {
    s_sum[wid] = lsum;
    s_cnt[wid] = lcnt;
  }
  __syncthreads();

  if (threadIdx.x == 0) {
    float ts = s_sum[0] + s_sum[1] + s_sum[2] + s_sum[3];
    float tc = s_cnt[0] + s_cnt[1] + s_cnt[2] + s_cnt[3];
    partials[2 * blockIdx.x] = ts;       // plain store — no atomics
    partials[2 * blockIdx.x + 1] = tc;
  }
}

__global__ __launch_bounds__(256) void ce_final_kernel(
    const float* __restrict__ partials, float* __restrict__ out, int nblocks) {
  float lsum = 0.0f;
  float lcnt = 0.0f;
  for (int j = threadIdx.x; j < nblocks; j += 256) {
    lsum += partials[2 * j];
    lcnt += partials[2 * j + 1];
  }
  for (int off = 32; off > 0; off >>= 1) {
    lsum += __shfl_down(lsum, off, 64);
    lcnt += __shfl_down(lcnt, off, 64);
  }
  __shared__ float s_sum[4];
  __shared__ float s_cnt[4];
  int wid = threadIdx.x >> 6;
  int lane = threadIdx.x & 63;
  if (lane == 0) {
    s_sum[wid] = lsum;
    s_cnt[wid] = lcnt;
  }
  __syncthreads();
  if (threadIdx.x == 0) {
    float ts = s_sum[0] + s_sum[1] + s_sum[2] + s_sum[3];
    float tc = s_cnt[0] + s_cnt[1] + s_cnt[2] + s_cnt[3];
    out[0] = ts / tc;
  }
}

extern "C" void kernel_launch(void* const* d_in, const int* in_sizes, int n_in,
                              void* d_out, int out_size, void* d_ws, size_t ws_size,
                              hipStream_t stream) {
  const float* pred = (const float*)d_in[0];
  const int* target = (const int*)d_in[1];
  const int* me = (const int*)d_in[2];
  float* partials = (float*)d_ws;   // every slot rewritten each launch; no memset needed
  float* out = (float*)d_out;

  int total_pixels = in_sizes[1];       // B*H*W = 4,194,304
  int n_groups = total_pixels >> 2;     // 4 pixels per thread-iteration

  ce_main_kernel<<<NBLOCKS, 256, 0, stream>>>(pred, target, me, partials, n_groups);
  ce_final_kernel<<<1, 256, 0, stream>>>(partials, out, NBLOCKS);
}